// Round 5
// baseline (980.030 us; speedup 1.0000x reference)
//
#include <hip/hip_runtime.h>
#include <math.h>

#define T_TOKENS 32768
#define DIM 2048
#define N_EXPERTS 256
#define N_GROUPS 8
#define EPG 32
#define TOPK 8
#define TOPK_GROUPS 4
#define ROUTE_SCALE 2.5f

#define BM 64           // tokens per block (block tile: 64 x 256 experts)
#define BK 32           // K-tile
#define KP 40           // padded LDS row (fp16 elems): 80B stride -> 2-way banks
#define KITERS (DIM / BK)
#define W_SCALE 256.0f  // pre-scale W so w_lo stays normal in fp16
#define INV_W_SCALE (1.0f / 256.0f)

typedef unsigned short u16;
typedef _Float16 f16x8 __attribute__((ext_vector_type(8)));
typedef float f32x4 __attribute__((ext_vector_type(4)));

__device__ __forceinline__ u16 f16_bits(_Float16 h) {
    union { _Float16 f; u16 u; } c; c.f = h; return c.u;
}

// ---------------------------------------------------------------------------
// Kernel 1: split 256*W (fp32) into fp16 hi/lo planes. 2 MB, L2-resident.
// ---------------------------------------------------------------------------
__global__ __launch_bounds__(256) void convert_w(
    const float* __restrict__ W, u16* __restrict__ Whi, u16* __restrict__ Wlo)
{
    const int i = blockIdx.x * 256 + threadIdx.x;   // 524288 total
    const float x = W[i] * W_SCALE;
    const _Float16 hi = (_Float16)x;
    const _Float16 lo = (_Float16)(x - (float)hi);
    Whi[i] = f16_bits(hi);
    Wlo[i] = f16_bits(lo);
}

// ---------------------------------------------------------------------------
// Kernel 2: fused sigmoid(X@W^T)+bias -> group-limited top-k routing.
// 256 thr (4 waves, wave tile 64x64), block tile 64 tokens x 256 experts.
// grid 512 = 2 blocks/CU: independent barrier domains overlap stalls.
// Split-fp16 3-term MFMA (hh+hl+lh), term-OUTERMOST for independent chains.
// ---------------------------------------------------------------------------
__global__ __launch_bounds__(256, 2) void fused_gate(
    const float* __restrict__ X,
    const u16* __restrict__ Whi, const u16* __restrict__ Wlo,
    const float* __restrict__ bias,
    float* __restrict__ out_w, float* __restrict__ out_i)
{
    __shared__ __align__(16) char smem[65536];   // staging union Sc
    __shared__ float bsh[N_EXPERTS];             // bias, survives the union
    u16* Ahi = (u16*)smem;            // [64][KP]    5120 B
    u16* Alo = Ahi + BM * KP;         // [64][KP]    5120 B
    u16* Bhi = Alo + BM * KP;         // [256][KP]  20480 B
    u16* Blo = Bhi + N_EXPERTS * KP;  // [256][KP]  20480 B  (51200 total)
    float* Sc = (float*)smem;         // epilogue alias: [64][256] fp32 = 65536 B

    const int tid = threadIdx.x;
    const int m0 = blockIdx.x * BM;

    bsh[tid] = bias[tid];

    // --- staging assignment ---
    const int xr = tid >> 2;          // X row 0..63
    const int xc = (tid & 3) * 8;     // k offset (floats): 4 thr x 8 = 32
    const float* xp = X + (size_t)(m0 + xr) * DIM + xc;
    const u16* whp = Whi + (size_t)tid * DIM;   // B row = tid (0..255)
    const u16* wlp = Wlo + (size_t)tid * DIM;

    // --- wave / fragment assignment ---
    const int lane = tid & 63;
    const int wn = tid >> 6;          // wave 0..3: expert quarter
    const int l16 = lane & 15;
    const int quad = lane >> 4;

    f32x4 acc[4][4];
    #pragma unroll
    for (int i = 0; i < 4; i++)
        #pragma unroll
        for (int j = 0; j < 4; j++) acc[i][j] = (f32x4){0.f, 0.f, 0.f, 0.f};

    // prefetch tile 0 into registers (kept live across MFMA section)
    float4 ax0 = *(const float4*)(xp);
    float4 ax1 = *(const float4*)(xp + 4);
    uint4 bh[4], bl[4];
    #pragma unroll
    for (int c = 0; c < 4; c++) {
        bh[c] = *(const uint4*)(whp + c * 8);
        bl[c] = *(const uint4*)(wlp + c * 8);
    }

    for (int it = 0; it < KITERS; ++it) {
        __syncthreads();   // all waves done reading LDS of previous tile
        // --- split A (fp32 -> fp16 hi/lo) + store; store B planes ---
        {
            ushort4 h0, l0, h1, l1;
            _Float16 t;
            t = (_Float16)ax0.x; h0.x = f16_bits(t); l0.x = f16_bits((_Float16)(ax0.x - (float)t));
            t = (_Float16)ax0.y; h0.y = f16_bits(t); l0.y = f16_bits((_Float16)(ax0.y - (float)t));
            t = (_Float16)ax0.z; h0.z = f16_bits(t); l0.z = f16_bits((_Float16)(ax0.z - (float)t));
            t = (_Float16)ax0.w; h0.w = f16_bits(t); l0.w = f16_bits((_Float16)(ax0.w - (float)t));
            t = (_Float16)ax1.x; h1.x = f16_bits(t); l1.x = f16_bits((_Float16)(ax1.x - (float)t));
            t = (_Float16)ax1.y; h1.y = f16_bits(t); l1.y = f16_bits((_Float16)(ax1.y - (float)t));
            t = (_Float16)ax1.z; h1.z = f16_bits(t); l1.z = f16_bits((_Float16)(ax1.z - (float)t));
            t = (_Float16)ax1.w; h1.w = f16_bits(t); l1.w = f16_bits((_Float16)(ax1.w - (float)t));
            *(ushort4*)&Ahi[xr * KP + xc]     = h0;
            *(ushort4*)&Ahi[xr * KP + xc + 4] = h1;
            *(ushort4*)&Alo[xr * KP + xc]     = l0;
            *(ushort4*)&Alo[xr * KP + xc + 4] = l1;
        }
        #pragma unroll
        for (int c = 0; c < 4; c++) {
            *(uint4*)&Bhi[tid * KP + c * 8] = bh[c];
            *(uint4*)&Blo[tid * KP + c * 8] = bl[c];
        }
        __syncthreads();

        // --- unconditional prefetch of next tile (mod wraps to tile 0) ---
        {
            const int ko = ((it + 1) & (KITERS - 1)) * BK;
            ax0 = *(const float4*)(xp + ko);
            ax1 = *(const float4*)(xp + ko + 4);
            #pragma unroll
            for (int c = 0; c < 4; c++) {
                bh[c] = *(const uint4*)(whp + ko + c * 8);
                bl[c] = *(const uint4*)(wlp + ko + c * 8);
            }
        }

        // --- LDS -> fragments (ds_read_b128, 80B stride: 2-way = free) ---
        f16x8 fah[4], fal[4], fbh[4], fbl[4];
        #pragma unroll
        for (int i = 0; i < 4; i++) {
            fah[i] = *(const f16x8*)&Ahi[(i * 16 + l16) * KP + quad * 8];
            fal[i] = *(const f16x8*)&Alo[(i * 16 + l16) * KP + quad * 8];
            const int nrow = wn * 64 + i * 16 + l16;
            fbh[i] = *(const f16x8*)&Bhi[nrow * KP + quad * 8];
            fbl[i] = *(const f16x8*)&Blo[nrow * KP + quad * 8];
        }
        // --- 3-term split-fp16 MFMA, term-outermost: 16 independent per group
        #pragma unroll
        for (int i = 0; i < 4; i++)
            #pragma unroll
            for (int j = 0; j < 4; j++)
                acc[i][j] = __builtin_amdgcn_mfma_f32_16x16x32_f16(fah[i], fbh[j], acc[i][j], 0, 0, 0);
        #pragma unroll
        for (int i = 0; i < 4; i++)
            #pragma unroll
            for (int j = 0; j < 4; j++)
                acc[i][j] = __builtin_amdgcn_mfma_f32_16x16x32_f16(fah[i], fbl[j], acc[i][j], 0, 0, 0);
        #pragma unroll
        for (int i = 0; i < 4; i++)
            #pragma unroll
            for (int j = 0; j < 4; j++)
                acc[i][j] = __builtin_amdgcn_mfma_f32_16x16x32_f16(fal[i], fbh[j], acc[i][j], 0, 0, 0);
    }

    // --- epilogue: biased sigmoid scores -> LDS (aliases staging) ---
    __syncthreads();   // last tile's ds_reads complete before overwrite
    #pragma unroll
    for (int i = 0; i < 4; i++)
        #pragma unroll
        for (int j = 0; j < 4; j++) {
            const int e = wn * 64 + j * 16 + l16;     // expert (C-layout col)
            const float bv = bsh[e];
            #pragma unroll
            for (int r = 0; r < 4; r++) {
                const int trow = i * 16 + quad * 4 + r;   // token (C-layout row)
                const float logit = acc[i][j][r] * INV_W_SCALE;
                Sc[trow * N_EXPERTS + e] = 1.f / (1.f + expf(-logit)) + bv;
            }
        }
    __syncthreads();

    // --- routing: one wave, one token per lane; staggered conflict-free LDS
    if (tid < 64) {
        const float* row = Sc + tid * N_EXPERTS;

        float gs[N_GROUPS];
        #pragma unroll
        for (int g = 0; g < N_GROUPS; g++) {
            float m1 = -INFINITY, m2 = -INFINITY;
            for (int jj = 0; jj < EPG; jj++) {
                const float v = row[g * EPG + ((tid + jj) & (EPG - 1))];
                if (v > m1) { m2 = m1; m1 = v; }
                else if (v > m2) { m2 = v; }
            }
            gs[g] = m1 + m2;
        }
        unsigned keep = 0;
        #pragma unroll
        for (int g = 0; g < N_GROUPS; g++) {
            int cnt = 0;
            #pragma unroll
            for (int h = 0; h < N_GROUPS; h++)
                if (gs[h] > gs[g] || (gs[h] == gs[g] && h < g)) cnt++;
            if (cnt < TOPK_GROUPS) keep |= (1u << g);
        }
        // top-8; comparator (v desc, idx asc) -> scan-order independent
        float tv[TOPK]; int ti[TOPK];
        #pragma unroll
        for (int i = 0; i < TOPK; i++) { tv[i] = -INFINITY; ti[i] = 0x7fffffff; }
        for (int g = 0; g < N_GROUPS; g++) {
            if (!(keep & (1u << g))) continue;
            for (int jj = 0; jj < EPG; jj++) {
                const int e = g * EPG + ((tid + jj) & (EPG - 1));
                const float v = row[e];
                if (v > tv[TOPK - 1] || (v == tv[TOPK - 1] && e < ti[TOPK - 1])) {
                    float cv = v; int ce = e;
                    #pragma unroll
                    for (int s = 0; s < TOPK; s++) {
                        const bool b = (cv > tv[s]) || (cv == tv[s] && ce < ti[s]);
                        if (b) {
                            const float t1 = tv[s]; tv[s] = cv; cv = t1;
                            const int t2 = ti[s]; ti[s] = ce; ce = t2;
                        }
                    }
                }
            }
        }
        float w[TOPK], sum = 0.f;
        #pragma unroll
        for (int i = 0; i < TOPK; i++) {
            w[i] = row[ti[i]] - bsh[ti[i]];   // raw sigmoid score
            sum += w[i];
        }
        const float scale = ROUTE_SCALE / fmaxf(sum, 1e-10f);
        const size_t t = (size_t)m0 + tid;
        #pragma unroll
        for (int i = 0; i < TOPK; i++) {
            out_w[t * TOPK + i] = w[i] * scale;
            out_i[t * TOPK + i] = (float)ti[i];
        }
    }
}

extern "C" void kernel_launch(void* const* d_in, const int* in_sizes, int n_in,
                              void* d_out, int out_size, void* d_ws, size_t ws_size,
                              hipStream_t stream)
{
    const float* x = (const float*)d_in[0];     // (T, D)
    const float* w = (const float*)d_in[1];     // (E, D)
    const float* b = (const float*)d_in[2];     // (E,)

    u16* whi = (u16*)d_ws;                      // (E, D) fp16 hi plane, 1 MB
    u16* wlo = whi + (size_t)N_EXPERTS * DIM;   // (E, D) fp16 lo plane, 1 MB

    float* out_w = (float*)d_out;                              // (T, 8)
    float* out_i = (float*)d_out + (size_t)T_TOKENS * TOPK;    // (T, 8) as fp32

    convert_w<<<(N_EXPERTS * DIM) / 256, 256, 0, stream>>>(w, whi, wlo);
    fused_gate<<<T_TOKENS / BM, 256, 0, stream>>>(x, whi, wlo, b, out_w, out_i);
}